// Round 2
// baseline (670.047 us; speedup 1.0000x reference)
//
#include <hip/hip_runtime.h>
#include <stdint.h>

typedef unsigned short u16;
typedef short bf16x8 __attribute__((ext_vector_type(8)));
typedef float f32x4 __attribute__((ext_vector_type(4)));
typedef u16 u16x4 __attribute__((ext_vector_type(4)));

__device__ __forceinline__ u16 f2bf(float f) {
    union { float f; unsigned int i; } v; v.f = f;
    unsigned int x = v.i;
    return (u16)((x + 0x7FFFu + ((x >> 16) & 1u)) >> 16);  // RNE
}

// Async global->LDS, 16B per lane. LDS dest is wave-uniform base; HW adds lane*16.
__device__ __forceinline__ void async_load16(const u16* g, u16* lds) {
    __builtin_amdgcn_global_load_lds(
        (const __attribute__((address_space(1))) unsigned int*)g,
        (__attribute__((address_space(3))) unsigned int*)lds,
        16, 0, 0);
}

// ---------------------------------------------------------------------------
// Gt[col][row] (4096 x 4096 bf16) from f32 BTT cores.
//   col = y1*256 + x1*16 + x2,  row r = j*256+i
//   G[r,col] = sum_c c2[(r*16+x2)*8+c] * sum_b c1[(r*16+x1)*64+c*8+b] * c0[(r*16+y1)*8+b]
// One block per (y1,x1); threads sweep r so Gt writes are coalesced.
// ---------------------------------------------------------------------------
__global__ void build_gt(const float* __restrict__ c0, const float* __restrict__ c1,
                         const float* __restrict__ c2, u16* __restrict__ Gt) {
    const int y1  = blockIdx.x >> 4;
    const int x1  = blockIdx.x & 15;
    const int tid = threadIdx.x;
    for (int p = 0; p < 16; ++p) {
        const int r = p * 256 + tid;
        float a0[8];
        {
            f32x4 v0 = *(const f32x4*)(c0 + ((size_t)r * 16 + y1) * 8);
            f32x4 v1 = *(const f32x4*)(c0 + ((size_t)r * 16 + y1) * 8 + 4);
            #pragma unroll
            for (int b = 0; b < 4; ++b) { a0[b] = v0[b]; a0[4 + b] = v1[b]; }
        }
        float t[8];
        const float* c1row = c1 + ((size_t)r * 16 + x1) * 64;
        #pragma unroll
        for (int c = 0; c < 8; ++c) {
            f32x4 v0 = *(const f32x4*)(c1row + c * 8);
            f32x4 v1 = *(const f32x4*)(c1row + c * 8 + 4);
            float s = 0.f;
            #pragma unroll
            for (int b = 0; b < 4; ++b) s += v0[b] * a0[b] + v1[b] * a0[4 + b];
            t[c] = s;
        }
        const float* c2row = c2 + (size_t)r * 128;
        #pragma unroll
        for (int x2 = 0; x2 < 16; ++x2) {
            f32x4 v0 = *(const f32x4*)(c2row + x2 * 8);
            f32x4 v1 = *(const f32x4*)(c2row + x2 * 8 + 4);
            float s = 0.f;
            #pragma unroll
            for (int c = 0; c < 4; ++c) s += v0[c] * t[c] + v1[c] * t[4 + c];
            Gt[((size_t)(blockIdx.x * 16 + x2)) * 4096 + r] = f2bf(s);
        }
    }
}

// X: f32 -> bf16, vectorized. n4 = number of float4 groups.
__global__ void conv_x(const f32x4* __restrict__ x, u16* __restrict__ xb, int n4) {
    for (int i = blockIdx.x * 256 + threadIdx.x; i < n4; i += gridDim.x * 256) {
        f32x4 v = x[i];
        u16x4 o;
        #pragma unroll
        for (int j = 0; j < 4; ++j) o[j] = f2bf(v[j]);
        *(u16x4*)(xb + 4 * (size_t)i) = o;
    }
}

// ---------------------------------------------------------------------------
// C[M,N] = X[M,K] @ Gt[N,K]^T + bias.  M=8192, N=K=4096. fp32 acc/out.
// XF32=false: X pre-converted bf16, full global_load_lds staging (m97).
// XF32=true : X is f32; A staged via VGPR cvt + ds_write (32MB-ws fallback).
// ---------------------------------------------------------------------------
#define TM 128
#define TN 128
#define BK 32

template <bool XF32>
__global__ void gemm_bt(const void* __restrict__ Xv, const u16* __restrict__ Gt,
                        const float* __restrict__ bias, float* __restrict__ out) {
    constexpr int K = 4096, N = 4096;
    __shared__ __attribute__((aligned(16))) u16 As[TM * BK];
    __shared__ __attribute__((aligned(16))) u16 Bs[TN * BK];

    const int tid  = threadIdx.x;
    const int lane = tid & 63;
    const int w    = tid >> 6;
    const int m0   = blockIdx.y * TM;
    const int n0   = blockIdx.x * TN;
    const int wm   = (w >> 1) * 64;
    const int wn   = (w & 1) * 64;
    const int lr   = lane & 15;
    const int lk   = (lane >> 4) * 8;

    f32x4 acc[4][4] = {};

    // B staging (async): pass s = tid (+256): row = s/4, chunk = (s&3)*8 bf16
    const int srow   = tid >> 2;
    const int schunk = (tid & 3) * 8;
    const u16* grow0 = Gt + (size_t)(n0 + srow) * K + schunk;
    const u16* grow1 = Gt + (size_t)(n0 + 64 + srow) * K + schunk;
    u16* ldsB0 = &Bs[(tid & ~63) * 8];
    u16* ldsB1 = &Bs[(256 + (tid & ~63)) * 8];

    // A staging pointers
    const u16* xrow0 = nullptr; const u16* xrow1 = nullptr;
    u16* ldsA0 = nullptr; u16* ldsA1 = nullptr;
    const float* xsrc = nullptr; u16* adst = nullptr;
    if constexpr (!XF32) {
        const u16* Xb = (const u16*)Xv;
        xrow0 = Xb + (size_t)(m0 + srow) * K + schunk;
        xrow1 = Xb + (size_t)(m0 + 64 + srow) * K + schunk;
        ldsA0 = &As[(tid & ~63) * 8];
        ldsA1 = &As[(256 + (tid & ~63)) * 8];
    } else {
        // thread t -> row = t>>1 (0..127), k-segment = (t&1)*16
        const float* Xf = (const float*)Xv;
        xsrc = Xf + (size_t)(m0 + (tid >> 1)) * K + (tid & 1) * 16;
        adst = &As[(tid >> 1) * BK + (tid & 1) * 16];
    }

    for (int k0 = 0; k0 < K; k0 += BK) {
        __syncthreads();
        if constexpr (!XF32) {
            async_load16(xrow0 + k0, ldsA0);
            async_load16(xrow1 + k0, ldsA1);
        } else {
            f32x4 v0 = ((const f32x4*)(xsrc + k0))[0];
            f32x4 v1 = ((const f32x4*)(xsrc + k0))[1];
            f32x4 v2 = ((const f32x4*)(xsrc + k0))[2];
            f32x4 v3 = ((const f32x4*)(xsrc + k0))[3];
            bf16x8 w0, w1;
            #pragma unroll
            for (int j = 0; j < 4; ++j) {
                w0[j]     = (short)f2bf(v0[j]);
                w0[4 + j] = (short)f2bf(v1[j]);
                w1[j]     = (short)f2bf(v2[j]);
                w1[4 + j] = (short)f2bf(v3[j]);
            }
            *(bf16x8*)adst = w0;
            *(bf16x8*)(adst + 8) = w1;
        }
        async_load16(grow0 + k0, ldsB0);
        async_load16(grow1 + k0, ldsB1);
        __syncthreads();

        bf16x8 af[4], bg[4];
        #pragma unroll
        for (int i = 0; i < 4; ++i) {
            af[i] = *(const bf16x8*)(&As[(wm + i * 16 + lr) * BK + lk]);
            bg[i] = *(const bf16x8*)(&Bs[(wn + i * 16 + lr) * BK + lk]);
        }
        #pragma unroll
        for (int mt = 0; mt < 4; ++mt)
            #pragma unroll
            for (int nt = 0; nt < 4; ++nt)
                acc[mt][nt] = __builtin_amdgcn_mfma_f32_16x16x32_bf16(
                    af[mt], bg[nt], acc[mt][nt], 0, 0, 0);
    }

    // Epilogue: C/D layout col = lane&15, row = (lane>>4)*4 + reg. f32 out + bias.
    #pragma unroll
    for (int nt = 0; nt < 4; ++nt) {
        const int n = n0 + wn + nt * 16 + lr;
        const float bv = bias[n];
        #pragma unroll
        for (int mt = 0; mt < 4; ++mt) {
            const int mbase = m0 + wm + mt * 16 + (lane >> 4) * 4;
            #pragma unroll
            for (int r = 0; r < 4; ++r) {
                out[(size_t)(mbase + r) * N + n] = acc[mt][nt][r] + bv;
            }
        }
    }
}

extern "C" void kernel_launch(void* const* d_in, const int* in_sizes, int n_in,
                              void* d_out, int out_size, void* d_ws, size_t ws_size,
                              hipStream_t stream) {
    const float* x    = (const float*)d_in[0];  // (8,1024,4096) f32
    const float* c0   = (const float*)d_in[1];  // 16^4*8 f32
    const float* c1   = (const float*)d_in[2];  // 16^4*64 f32
    const float* c2   = (const float*)d_in[3];  // 16^4*8 f32
    const float* bias = (const float*)d_in[4];  // 4096 f32
    float* out = (float*)d_out;

    const size_t GT_BYTES = (size_t)4096 * 4096 * sizeof(u16);   // 32 MB
    const size_t XB_BYTES = (size_t)8192 * 4096 * sizeof(u16);   // 64 MB
    u16* Gt = (u16*)d_ws;

    build_gt<<<256, 256, 0, stream>>>(c0, c1, c2, Gt);

    dim3 grid(4096 / TN, 8192 / TM);  // (32, 64)
    if (ws_size >= GT_BYTES + XB_BYTES) {
        u16* Xb = (u16*)((char*)d_ws + GT_BYTES);
        conv_x<<<8192, 256, 0, stream>>>((const f32x4*)x, Xb, 8192 * 4096 / 4);
        gemm_bt<false><<<grid, 256, 0, stream>>>(Xb, Gt, bias, out);
    } else {
        gemm_bt<true><<<grid, 256, 0, stream>>>(x, Gt, bias, out);
    }
}

// Round 3
// 648.697 us; speedup vs baseline: 1.0329x; 1.0329x over previous
//
#include <hip/hip_runtime.h>
#include <stdint.h>

typedef unsigned short u16;
typedef short bf16x8 __attribute__((ext_vector_type(8)));
typedef float f32x4 __attribute__((ext_vector_type(4)));
typedef u16 u16x4 __attribute__((ext_vector_type(4)));

__device__ __forceinline__ u16 f2bf(float f) {
    union { float f; unsigned int i; } v; v.f = f;
    unsigned int x = v.i;
    return (u16)((x + 0x7FFFu + ((x >> 16) & 1u)) >> 16);  // RNE
}

// Async global->LDS, 16B per lane. LDS dest is wave-uniform base; HW adds lane*16.
__device__ __forceinline__ void async_load16(const u16* g, u16* lds) {
    __builtin_amdgcn_global_load_lds(
        (const __attribute__((address_space(1))) unsigned int*)g,
        (__attribute__((address_space(3))) unsigned int*)lds,
        16, 0, 0);
}

// ---------------------------------------------------------------------------
// Gt[col][row] (4096 x 4096 bf16) from f32 BTT cores.
//   col = y1*256 + x1*16 + x2,  row r = j*256+i
//   G[r,col] = sum_c c2[(r*16+x2)*8+c] * sum_b c1[(r*16+x1)*64+c*8+b] * c0[(r*16+y1)*8+b]
// grid (256,16): blockIdx.x=(y1,x1), blockIdx.y=p, r=p*256+tid.
// 4096 blocks = 16/CU for latency hiding (cores are L2/L3-resident).
// ---------------------------------------------------------------------------
__global__ void build_gt(const float* __restrict__ c0, const float* __restrict__ c1,
                         const float* __restrict__ c2, u16* __restrict__ Gt) {
    const int y1  = blockIdx.x >> 4;
    const int x1  = blockIdx.x & 15;
    const int r   = blockIdx.y * 256 + threadIdx.x;

    float a0[8];
    {
        f32x4 v0 = *(const f32x4*)(c0 + ((size_t)r * 16 + y1) * 8);
        f32x4 v1 = *(const f32x4*)(c0 + ((size_t)r * 16 + y1) * 8 + 4);
        #pragma unroll
        for (int b = 0; b < 4; ++b) { a0[b] = v0[b]; a0[4 + b] = v1[b]; }
    }
    float t[8];
    const float* c1row = c1 + ((size_t)r * 16 + x1) * 64;
    #pragma unroll
    for (int c = 0; c < 8; ++c) {
        f32x4 v0 = *(const f32x4*)(c1row + c * 8);
        f32x4 v1 = *(const f32x4*)(c1row + c * 8 + 4);
        float s = 0.f;
        #pragma unroll
        for (int b = 0; b < 4; ++b) s += v0[b] * a0[b] + v1[b] * a0[4 + b];
        t[c] = s;
    }
    const float* c2row = c2 + (size_t)r * 128;
    #pragma unroll
    for (int x2 = 0; x2 < 16; ++x2) {
        f32x4 v0 = *(const f32x4*)(c2row + x2 * 8);
        f32x4 v1 = *(const f32x4*)(c2row + x2 * 8 + 4);
        float s = 0.f;
        #pragma unroll
        for (int c = 0; c < 4; ++c) s += v0[c] * t[c] + v1[c] * t[4 + c];
        Gt[((size_t)(blockIdx.x * 16 + x2)) * 4096 + r] = f2bf(s);
    }
}

// X: f32 -> bf16, vectorized. n4 = number of float4 groups.
__global__ void conv_x(const f32x4* __restrict__ x, u16* __restrict__ xb, int n4) {
    for (int i = blockIdx.x * 256 + threadIdx.x; i < n4; i += gridDim.x * 256) {
        f32x4 v = x[i];
        u16x4 o;
        #pragma unroll
        for (int j = 0; j < 4; ++j) o[j] = f2bf(v[j]);
        *(u16x4*)(xb + 4 * (size_t)i) = o;
    }
}

// ---------------------------------------------------------------------------
// C[M,N] = X[M,K] @ Gt[N,K]^T + bias.  M=8192, N=K=4096. fp32 acc/out.
// XF32=false: X pre-converted bf16, full global_load_lds staging (m97).
// XF32=true : X is f32; A staged via VGPR cvt + ds_write (32MB-ws fallback).
// ---------------------------------------------------------------------------
#define TM 128
#define TN 128
#define BK 32

template <bool XF32>
__global__ void gemm_bt(const void* __restrict__ Xv, const u16* __restrict__ Gt,
                        const float* __restrict__ bias, float* __restrict__ out) {
    constexpr int K = 4096, N = 4096;
    __shared__ __attribute__((aligned(16))) u16 As[TM * BK];
    __shared__ __attribute__((aligned(16))) u16 Bs[TN * BK];

    const int tid  = threadIdx.x;
    const int lane = tid & 63;
    const int w    = tid >> 6;
    const int m0   = blockIdx.y * TM;
    const int n0   = blockIdx.x * TN;
    const int wm   = (w >> 1) * 64;
    const int wn   = (w & 1) * 64;
    const int lr   = lane & 15;
    const int lk   = (lane >> 4) * 8;

    f32x4 acc[4][4] = {};

    // B staging (async): pass s = tid (+256): row = s/4, chunk = (s&3)*8 bf16
    const int srow   = tid >> 2;
    const int schunk = (tid & 3) * 8;
    const u16* grow0 = Gt + (size_t)(n0 + srow) * K + schunk;
    const u16* grow1 = Gt + (size_t)(n0 + 64 + srow) * K + schunk;
    u16* ldsB0 = &Bs[(tid & ~63) * 8];
    u16* ldsB1 = &Bs[(256 + (tid & ~63)) * 8];

    // A staging pointers
    const u16* xrow0 = nullptr; const u16* xrow1 = nullptr;
    u16* ldsA0 = nullptr; u16* ldsA1 = nullptr;
    const float* xsrc = nullptr; u16* adst = nullptr;
    if constexpr (!XF32) {
        const u16* Xb = (const u16*)Xv;
        xrow0 = Xb + (size_t)(m0 + srow) * K + schunk;
        xrow1 = Xb + (size_t)(m0 + 64 + srow) * K + schunk;
        ldsA0 = &As[(tid & ~63) * 8];
        ldsA1 = &As[(256 + (tid & ~63)) * 8];
    } else {
        const float* Xf = (const float*)Xv;
        xsrc = Xf + (size_t)(m0 + (tid >> 1)) * K + (tid & 1) * 16;
        adst = &As[(tid >> 1) * BK + (tid & 1) * 16];
    }

    for (int k0 = 0; k0 < K; k0 += BK) {
        __syncthreads();
        if constexpr (!XF32) {
            async_load16(xrow0 + k0, ldsA0);
            async_load16(xrow1 + k0, ldsA1);
        } else {
            f32x4 v0 = ((const f32x4*)(xsrc + k0))[0];
            f32x4 v1 = ((const f32x4*)(xsrc + k0))[1];
            f32x4 v2 = ((const f32x4*)(xsrc + k0))[2];
            f32x4 v3 = ((const f32x4*)(xsrc + k0))[3];
            bf16x8 w0, w1;
            #pragma unroll
            for (int j = 0; j < 4; ++j) {
                w0[j]     = (short)f2bf(v0[j]);
                w0[4 + j] = (short)f2bf(v1[j]);
                w1[j]     = (short)f2bf(v2[j]);
                w1[4 + j] = (short)f2bf(v3[j]);
            }
            *(bf16x8*)adst = w0;
            *(bf16x8*)(adst + 8) = w1;
        }
        async_load16(grow0 + k0, ldsB0);
        async_load16(grow1 + k0, ldsB1);
        __syncthreads();

        bf16x8 af[4], bg[4];
        #pragma unroll
        for (int i = 0; i < 4; ++i) {
            af[i] = *(const bf16x8*)(&As[(wm + i * 16 + lr) * BK + lk]);
            bg[i] = *(const bf16x8*)(&Bs[(wn + i * 16 + lr) * BK + lk]);
        }
        #pragma unroll
        for (int mt = 0; mt < 4; ++mt)
            #pragma unroll
            for (int nt = 0; nt < 4; ++nt)
                acc[mt][nt] = __builtin_amdgcn_mfma_f32_16x16x32_bf16(
                    af[mt], bg[nt], acc[mt][nt], 0, 0, 0);
    }

    // Epilogue: C/D layout col = lane&15, row = (lane>>4)*4 + reg. f32 out + bias.
    #pragma unroll
    for (int nt = 0; nt < 4; ++nt) {
        const int n = n0 + wn + nt * 16 + lr;
        const float bv = bias[n];
        #pragma unroll
        for (int mt = 0; mt < 4; ++mt) {
            const int mbase = m0 + wm + mt * 16 + (lane >> 4) * 4;
            #pragma unroll
            for (int r = 0; r < 4; ++r) {
                out[(size_t)(mbase + r) * N + n] = acc[mt][nt][r] + bv;
            }
        }
    }
}

extern "C" void kernel_launch(void* const* d_in, const int* in_sizes, int n_in,
                              void* d_out, int out_size, void* d_ws, size_t ws_size,
                              hipStream_t stream) {
    const float* x    = (const float*)d_in[0];  // (8,1024,4096) f32
    const float* c0   = (const float*)d_in[1];  // 16^4*8 f32
    const float* c1   = (const float*)d_in[2];  // 16^4*64 f32
    const float* c2   = (const float*)d_in[3];  // 16^4*8 f32
    const float* bias = (const float*)d_in[4];  // 4096 f32
    float* out = (float*)d_out;

    const size_t GT_BYTES = (size_t)4096 * 4096 * sizeof(u16);   // 32 MB
    const size_t XB_BYTES = (size_t)8192 * 4096 * sizeof(u16);   // 64 MB
    u16* Gt = (u16*)d_ws;

    build_gt<<<dim3(256, 16), 256, 0, stream>>>(c0, c1, c2, Gt);

    dim3 grid(4096 / TN, 8192 / TM);  // (32, 64)
    if (ws_size >= GT_BYTES + XB_BYTES) {
        u16* Xb = (u16*)((char*)d_ws + GT_BYTES);
        conv_x<<<8192, 256, 0, stream>>>((const f32x4*)x, Xb, 8192 * 4096 / 4);
        gemm_bt<false><<<grid, 256, 0, stream>>>(Xb, Gt, bias, out);
    } else {
        gemm_bt<true><<<grid, 256, 0, stream>>>(x, Gt, bias, out);
    }
}